// Round 1
// baseline (742.470 us; speedup 1.0000x reference)
//
#include <hip/hip_runtime.h>

#define IS2f 0.70710678118654752440f

// workspace offsets in floats (total 4,849,664 floats = ~18.5 MB)
#define WS_Z   0ul          // 1024 * 2048
#define WS_G   2097152ul    // 1024 * 1024
#define WS_H   3145728ul    // 1024 * 1024
#define WS_SU  4194304ul    // 131072: [ci][b][j][c][l]
#define WS_VV  4325376ul    // 524288: [ci][b][j][l][n]

__device__ __forceinline__ void decode_pid(int pid, int& ci, int& b, int& l, int& L){
  if (pid < 512)      { ci = 0; b = pid >> 7; l = pid & 127; L = 128; }
  else if (pid < 768) { int q = pid - 512; ci = 1; b = q >> 6; l = q & 63; L = 64; }
  else                { int q = pid - 768; ci = 2; b = q >> 6; l = q & 63; L = 64; }
}
__device__ __forceinline__ int su_base(int ci){ return ci==0 ? 0 : (ci==1 ? 65536 : 98304); }
__device__ __forceinline__ int vv_base(int ci){ return ci==0 ? 0 : (ci==1 ? 262144 : 393216); }

// ---------------------------------------------------------------------------
// Kernel 1: per problem (ci,b,l): M (64x256) -> Z=M*p (64x32), G=Z^T Z,
// B=Z^T M (LDS only), H=B B^T.  Store Z,G,H to ws.
// ---------------------------------------------------------------------------
__global__ __launch_bounds__(256) void k_fact(const float* __restrict__ x,
                                              const float* __restrict__ p,
                                              float* __restrict__ ws){
  __shared__ __align__(16) float Ms[64*256];
  __shared__ __align__(16) float Zs[64*32];
  __shared__ float Bt[256*33];               // B transposed: Bt[n][k], pad 33
  __shared__ __align__(16) float Ps[256*32];

  int pid = blockIdx.x, tid = threadIdx.x;
  int ci,b,l,L; decode_pid(pid,ci,b,l,L);

  // stage p (256x32)
  {
    const float4* p4 = (const float4*)p;
    float4* Ps4 = (float4*)Ps;
    #pragma unroll
    for (int e=0;e<8;++e) Ps4[tid + 256*e] = p4[tid + 256*e];
  }
  // load M with on-the-fly Haar combine.  x f4 layout: ((b*256+t)*64+c)*64+g
  const float4* x4 = (const float4*)x;
  float4* Ms4 = (float4*)Ms;
  if (ci == 0){
    size_t base = ((size_t)(b*256 + 2*l) * 64) * 64;
    #pragma unroll
    for (int e=0;e<16;++e){
      int f = tid + 256*e;
      float4 A = x4[base + f];
      float4 Bv = x4[base + 4096 + f];
      float4 m;
      m.x=(A.x-Bv.x)*IS2f; m.y=(A.y-Bv.y)*IS2f; m.z=(A.z-Bv.z)*IS2f; m.w=(A.w-Bv.w)*IS2f;
      Ms4[f] = m;
    }
  } else {
    float sg = (ci==1) ? -0.5f : 0.5f;
    size_t base = ((size_t)(b*256 + 4*l) * 64) * 64;
    #pragma unroll
    for (int e=0;e<16;++e){
      int f = tid + 256*e;
      float4 A = x4[base + f];
      float4 B1 = x4[base + 4096 + f];
      float4 C1 = x4[base + 8192 + f];
      float4 D1 = x4[base + 12288 + f];
      float4 m;
      m.x=(A.x+B1.x)*0.5f + (C1.x+D1.x)*sg;
      m.y=(A.y+B1.y)*0.5f + (C1.y+D1.y)*sg;
      m.z=(A.z+B1.z)*0.5f + (C1.z+D1.z)*sg;
      m.w=(A.w+B1.w)*0.5f + (C1.w+D1.w)*sg;
      Ms4[f] = m;
    }
  }
  __syncthreads();

  // Z[c][k] = sum_n M[c][n] * p[n][k];  thread: k = tid&31, c0 = tid>>5, c = c0*8+i
  {
    int k = tid & 31, c0 = tid >> 5;
    float acc[8] = {0,0,0,0,0,0,0,0};
    #pragma unroll 4
    for (int n4=0;n4<64;++n4){
      float p0 = Ps[(4*n4+0)*32 + k];
      float p1 = Ps[(4*n4+1)*32 + k];
      float p2 = Ps[(4*n4+2)*32 + k];
      float p3 = Ps[(4*n4+3)*32 + k];
      #pragma unroll
      for (int i=0;i<8;++i){
        float4 m = Ms4[(c0*8+i)*64 + n4];
        acc[i] += m.x*p0 + m.y*p1 + m.z*p2 + m.w*p3;
      }
    }
    #pragma unroll
    for (int i=0;i<8;++i){
      int c = c0*8 + i;
      Zs[c*32+k] = acc[i];
      ws[WS_Z + (size_t)pid*2048 + c*32 + k] = acc[i];
    }
  }
  __syncthreads();

  // G = Z^T Z (32x32)
  #pragma unroll
  for (int e=0;e<4;++e){
    int jk = tid + 256*e; int j = jk>>5, kk = jk&31;
    float a = 0.f;
    #pragma unroll 4
    for (int c=0;c<64;++c) a += Zs[c*32+j]*Zs[c*32+kk];
    ws[WS_G + (size_t)pid*1024 + jk] = a;
  }
  // B[k][n] = sum_c Z[c][k] M[c][n]  -> Bt[n][k]
  {
    int n4 = tid & 63, kg = tid >> 6;
    #pragma unroll
    for (int kq=0;kq<8;++kq){
      int kk = kg*8 + kq;
      float ax=0.f, ay=0.f, az=0.f, aw=0.f;
      #pragma unroll 4
      for (int c=0;c<64;++c){
        float zv = Zs[c*32+kk];
        float4 mv = Ms4[c*64 + n4];
        ax += zv*mv.x; ay += zv*mv.y; az += zv*mv.z; aw += zv*mv.w;
      }
      Bt[(n4*4+0)*33 + kk] = ax;
      Bt[(n4*4+1)*33 + kk] = ay;
      Bt[(n4*4+2)*33 + kk] = az;
      Bt[(n4*4+3)*33 + kk] = aw;
    }
  }
  __syncthreads();

  // H = B B^T (32x32)
  #pragma unroll
  for (int e=0;e<4;++e){
    int jk = tid + 256*e; int j = jk>>5, kk = jk&31;
    float a = 0.f;
    #pragma unroll 4
    for (int n=0;n<256;++n) a += Bt[n*33+j]*Bt[n*33+kk];
    ws[WS_H + (size_t)pid*1024 + jk] = a;
  }
}

// ---------------------------------------------------------------------------
// Kernel 2: per problem, 1 wave. Cholesky G=R^T R, W = R^-T H R^-1,
// parallel cyclic Jacobi eigensolve of W, top-2; g=R^-1 w, u=Z g,
// vh = u^T M / s (streams x).  Writes s*u and vh factor arrays.
// ---------------------------------------------------------------------------
#define NSWEEP 6

__global__ __launch_bounds__(64) void k_solve(const float* __restrict__ x,
                                              float* __restrict__ ws){
  __shared__ float Gs[32*33];
  __shared__ float Hs[32*33];
  __shared__ float Vsh[32*33];
  __shared__ float cA[16], sA[16];
  __shared__ int   pA[16], qA[16];
  __shared__ float rr2[2][32], gg[2][32];
  __shared__ float us[2][64];
  __shared__ int   topi[2];
  __shared__ float topl[2];

  int pid = blockIdx.x, lane = threadIdx.x;
  int ci,b,l,L; decode_pid(pid,ci,b,l,L);

  #pragma unroll
  for (int e=0;e<16;++e){
    int idx = lane + 64*e; int i = idx>>5, j = idx&31;
    Gs[i*33+j]  = ws[WS_G + (size_t)pid*1024 + idx];
    Hs[i*33+j]  = ws[WS_H + (size_t)pid*1024 + idx];
    Vsh[i*33+j] = (i==j) ? 1.f : 0.f;
  }
  __syncthreads();

  // Cholesky (upper) in Gs: G = R^T R
  for (int k=0;k<32;++k){
    float rkk  = sqrtf(Gs[k*33+k]);
    float rinv = 1.f/rkk;
    __syncthreads();
    if (lane == k) Gs[k*33+k] = rkk;
    if (lane > k && lane < 32) Gs[k*33+lane] *= rinv;
    __syncthreads();
    if (lane > k && lane < 32){
      float rkj = Gs[k*33+lane];
      for (int i=k+1;i<=lane;++i) Gs[i*33+lane] -= Gs[k*33+i]*rkj;
    }
    __syncthreads();
  }

  // X = R^-T H  (column j per lane, in place)
  if (lane < 32){
    int j = lane;
    for (int i=0;i<32;++i){
      float xv = Hs[i*33+j];
      for (int k=0;k<i;++k) xv -= Gs[k*33+i]*Hs[k*33+j];
      Hs[i*33+j] = xv / Gs[i*33+i];
    }
  }
  __syncthreads();
  // W = X R^-1  (row i per lane, in place)
  if (lane < 32){
    int i = lane;
    for (int j=0;j<32;++j){
      float wv = Hs[i*33+j];
      for (int k=0;k<j;++k) wv -= Hs[i*33+k]*Gs[k*33+j];
      Hs[i*33+j] = wv / Gs[j*33+j];
    }
  }
  __syncthreads();

  // parallel cyclic Jacobi (round-robin tournament, 16 disjoint pairs/round)
  for (int sw=0; sw<NSWEEP; ++sw){
    for (int r=0; r<31; ++r){
      if (lane < 16){
        int pp, qq;
        if (lane == 0){ pp = r; qq = 31; }
        else { pp = (r + lane) % 31; qq = (r + 31 - lane) % 31; }
        float app = Hs[pp*33+pp], aqq = Hs[qq*33+qq], apq = Hs[pp*33+qq];
        float cc = 1.f, ss = 0.f;
        if (fabsf(apq) > 1e-28f){
          float tau = (aqq - app) / (2.f*apq);
          float tt  = ((tau >= 0.f) ? 1.f : -1.f) / (fabsf(tau) + sqrtf(1.f + tau*tau));
          cc = 1.f / sqrtf(1.f + tt*tt);
          ss = tt * cc;
        }
        cA[lane]=cc; sA[lane]=ss; pA[lane]=pp; qA[lane]=qq;
      }
      __syncthreads();
      #pragma unroll
      for (int e=0;e<8;++e){                      // row phase: Y = G^T W
        int item = lane + 64*e; int m = item>>5; int i = item&31;
        int pp=pA[m], qq=qA[m]; float cc=cA[m], ss=sA[m];
        float wp = Hs[pp*33+i], wq = Hs[qq*33+i];
        Hs[pp*33+i] = cc*wp - ss*wq;
        Hs[qq*33+i] = ss*wp + cc*wq;
      }
      __syncthreads();
      #pragma unroll
      for (int e=0;e<8;++e){                      // col phase: W = Y G, V = V G
        int item = lane + 64*e; int m = item>>5; int i = item&31;
        int pp=pA[m], qq=qA[m]; float cc=cA[m], ss=sA[m];
        float wp = Hs[i*33+pp], wq = Hs[i*33+qq];
        Hs[i*33+pp] = cc*wp - ss*wq;
        Hs[i*33+qq] = ss*wp + cc*wq;
        float vp = Vsh[i*33+pp], vq = Vsh[i*33+qq];
        Vsh[i*33+pp] = cc*vp - ss*vq;
        Vsh[i*33+qq] = ss*vp + cc*vq;
      }
      __syncthreads();
    }
  }

  // top-2 eigenvalues
  if (lane == 0){
    float b0 = -1e30f; int i0 = 0;
    for (int i=0;i<32;++i){ float d = Hs[i*33+i]; if (d > b0){ b0 = d; i0 = i; } }
    float b1 = -1e30f; int i1 = (i0==0) ? 1 : 0;
    for (int i=0;i<32;++i){ if (i==i0) continue; float d = Hs[i*33+i]; if (d > b1){ b1 = d; i1 = i; } }
    topi[0]=i0; topi[1]=i1; topl[0]=b0; topl[1]=b1;
  }
  __syncthreads();

  // back-solve R g = w for both eigvecs in parallel (jj = lane>>5)
  {
    int jj = lane >> 5, ii = lane & 31;
    rr2[jj][ii] = Vsh[ii*33 + topi[jj]];
    __syncthreads();
    for (int i=31;i>=0;--i){
      if (ii == i) gg[jj][i] = rr2[jj][i] / Gs[i*33+i];
      __syncthreads();
      if (ii < i) rr2[jj][ii] -= Gs[ii*33+i] * gg[jj][i];
      __syncthreads();
    }
  }
  __syncthreads();

  float s0 = sqrtf(fmaxf(topl[0], 0.f)); if (s0 < 1e-12f) s0 = 1e-12f;
  float s1 = sqrtf(fmaxf(topl[1], 0.f)); if (s1 < 1e-12f) s1 = 1e-12f;

  // u = Z g (lane = c)
  {
    const float4* Z4 = (const float4*)(ws + WS_Z + (size_t)pid*2048);
    float u0 = 0.f, u1 = 0.f;
    #pragma unroll
    for (int k4=0;k4<8;++k4){
      float4 z = Z4[lane*8 + k4];
      u0 += z.x*gg[0][k4*4+0] + z.y*gg[0][k4*4+1] + z.z*gg[0][k4*4+2] + z.w*gg[0][k4*4+3];
      u1 += z.x*gg[1][k4*4+0] + z.y*gg[1][k4*4+1] + z.z*gg[1][k4*4+2] + z.w*gg[1][k4*4+3];
    }
    us[0][lane] = u0; us[1][lane] = u1;
    ws[WS_SU + su_base(ci) + ((size_t)(b*2+0)*64 + lane)*L + l] = s0*u0;
    ws[WS_SU + su_base(ci) + ((size_t)(b*2+1)*64 + lane)*L + l] = s1*u1;
  }
  __syncthreads();

  // vh_j = u_j^T M / s_j, streaming x (lane covers n = 4*lane .. 4*lane+3)
  {
    float a0x=0,a0y=0,a0z=0,a0w=0, a1x=0,a1y=0,a1z=0,a1w=0;
    const float4* x4 = (const float4*)x;
    if (ci == 0){
      size_t base = ((size_t)(b*256 + 2*l) * 64) * 64;
      #pragma unroll 2
      for (int c=0;c<64;++c){
        float4 A  = x4[base + c*64 + lane];
        float4 Bv = x4[base + 4096 + c*64 + lane];
        float mx=(A.x-Bv.x)*IS2f, my=(A.y-Bv.y)*IS2f, mz=(A.z-Bv.z)*IS2f, mw=(A.w-Bv.w)*IS2f;
        float uc0 = us[0][c], uc1 = us[1][c];
        a0x += uc0*mx; a0y += uc0*my; a0z += uc0*mz; a0w += uc0*mw;
        a1x += uc1*mx; a1y += uc1*my; a1z += uc1*mz; a1w += uc1*mw;
      }
    } else {
      float sg = (ci==1) ? -0.5f : 0.5f;
      size_t base = ((size_t)(b*256 + 4*l) * 64) * 64;
      #pragma unroll 2
      for (int c=0;c<64;++c){
        float4 A  = x4[base + c*64 + lane];
        float4 B1 = x4[base + 4096 + c*64 + lane];
        float4 C1 = x4[base + 8192 + c*64 + lane];
        float4 D1 = x4[base + 12288 + c*64 + lane];
        float mx=(A.x+B1.x)*0.5f + (C1.x+D1.x)*sg;
        float my=(A.y+B1.y)*0.5f + (C1.y+D1.y)*sg;
        float mz=(A.z+B1.z)*0.5f + (C1.z+D1.z)*sg;
        float mw=(A.w+B1.w)*0.5f + (C1.w+D1.w)*sg;
        float uc0 = us[0][c], uc1 = us[1][c];
        a0x += uc0*mx; a0y += uc0*my; a0z += uc0*mz; a0w += uc0*mw;
        a1x += uc1*mx; a1y += uc1*my; a1z += uc1*mz; a1w += uc1*mw;
      }
    }
    float i0 = 1.f/s0, i1 = 1.f/s1;
    size_t vb0 = WS_VV + vv_base(ci) + ((size_t)(b*2+0)*L + l)*256 + lane*4;
    size_t vb1 = WS_VV + vv_base(ci) + ((size_t)(b*2+1)*L + l)*256 + lane*4;
    ws[vb0+0]=a0x*i0; ws[vb0+1]=a0y*i0; ws[vb0+2]=a0z*i0; ws[vb0+3]=a0w*i0;
    ws[vb1+0]=a1x*i1; ws[vb1+1]=a1y*i1; ws[vb1+2]=a1z*i1; ws[vb1+3]=a1w*i1;
  }
}

// ---------------------------------------------------------------------------
// Kernel 3: writer. block = (ntile of 32 n, c, b). Recompute Haar coeffs in
// LDS, stage V slices, write all 9 slots with t-contiguous stores (+ zero pad).
// ---------------------------------------------------------------------------
__global__ __launch_bounds__(256) void k_out(const float* __restrict__ x,
                                             const float* __restrict__ ws,
                                             float* __restrict__ out){
  __shared__ float d1[128*33];
  __shared__ float d2[64*33];
  __shared__ float a2s[64*33];
  __shared__ float Vs[2*128*33];   // also aliased as a1 (first 128*33) during Haar
  __shared__ float Us[512];

  int nt = blockIdx.x, c = blockIdx.y, b = blockIdx.z;
  int n0 = nt * 32, tid = threadIdx.x;
  float* a1 = Vs;

  // pass1: level-1 Haar. items: 128 l1 x 8 d4 (float4 cols)
  const float4* x4 = (const float4*)x;
  #pragma unroll
  for (int e=0;e<4;++e){
    int f = tid + 256*e; int l1 = f>>3, d4 = f&7;
    size_t r = ((size_t)(b*256 + 2*l1)*64 + c)*64 + (n0>>2) + d4;
    float4 A = x4[r], Bv = x4[r + 4096];
    int o = l1*33 + 4*d4;
    d1[o+0]=(A.x-Bv.x)*IS2f; d1[o+1]=(A.y-Bv.y)*IS2f; d1[o+2]=(A.z-Bv.z)*IS2f; d1[o+3]=(A.w-Bv.w)*IS2f;
    a1[o+0]=(A.x+Bv.x)*IS2f; a1[o+1]=(A.y+Bv.y)*IS2f; a1[o+2]=(A.z+Bv.z)*IS2f; a1[o+3]=(A.w+Bv.w)*IS2f;
  }
  __syncthreads();
  // pass2: level-2 Haar from a1
  #pragma unroll
  for (int e=0;e<2;++e){
    int f = tid + 256*e; int l2 = f>>3, d4 = f&7;
    #pragma unroll
    for (int j=0;j<4;++j){
      int dn = 4*d4 + j;
      float aa = a1[(2*l2)*33 + dn], bb = a1[(2*l2+1)*33 + dn];
      d2[l2*33+dn]  = (aa-bb)*IS2f;
      a2s[l2*33+dn] = (aa+bb)*IS2f;
    }
  }
  // load Us: 512 entries, layout [ci0 j0 l(128) | ci0 j1 | ci1 j0 l(64) | ci1 j1 | ci2 j0 | ci2 j1]
  #pragma unroll
  for (int e=0;e<2;++e){
    int idx = tid + 256*e;
    int ci, j, l, L, so;
    if (idx < 256)      { ci=0; j=idx>>7;        l=idx&127; L=128; so=0; }
    else if (idx < 384) { ci=1; j=(idx-256)>>6;  l=idx&63;  L=64;  so=65536; }
    else                { ci=2; j=(idx-384)>>6;  l=idx&63;  L=64;  so=98304; }
    (void)ci;
    Us[idx] = ws[WS_SU + so + ((size_t)(b*2+j)*64 + c)*L + l];
  }
  __syncthreads();

  for (int cc=0; cc<3; ++cc){
    int L   = (cc==0) ? 128 : 64;
    int pad = 256 - L;
    int sb  = cc*3;
    int uo  = (cc==0) ? 0 : (cc==1) ? 256 : 384;
    const float* cf = (cc==0) ? d1 : (cc==1) ? d2 : a2s;

    // stage V slices: Vs[j][l][dn]
    int iters = (2*L*32) >> 8;
    for (int e=0;e<iters;++e){
      int idx = tid + 256*e;
      int j = (idx >= L*32) ? 1 : 0;
      int rem = idx - j*L*32;
      int ll = rem >> 5, dn = rem & 31;
      Vs[j*4224 + ll*33 + dn] =
        ws[WS_VV + vv_base(cc) + ((size_t)(b*2+j)*L + ll)*256 + n0 + dn];
    }
    __syncthreads();

    int l = tid - pad;
    bool inr = (l >= 0);
    size_t obase = (size_t)sb*16777216 + (size_t)b*4194304 + (size_t)c*65536
                 + (size_t)n0*256 + tid;
    #pragma unroll 4
    for (int dn=0; dn<32; ++dn){
      float v0 = 0.f, v1 = 0.f, rv = 0.f;
      if (inr){
        float q0 = Us[uo + l]     * Vs[l*33 + dn];
        float q1 = Us[uo + L + l] * Vs[4224 + l*33 + dn];
        v0 = q0; v1 = q1;
        rv = cf[l*33 + dn] - q0 - q1;
      }
      out[obase + dn*256]            = v0;
      out[obase + dn*256 + 16777216] = v1;
      out[obase + dn*256 + 33554432] = rv;
    }
    __syncthreads();
  }
}

// ---------------------------------------------------------------------------
extern "C" void kernel_launch(void* const* d_in, const int* in_sizes, int n_in,
                              void* d_out, int out_size, void* d_ws, size_t ws_size,
                              hipStream_t stream) {
  const float* x = (const float*)d_in[0];   // (4,256,64,256) f32
  const float* p = (const float*)d_in[1];   // (256,32) f32
  float* out = (float*)d_out;               // (9,4,64,256,256) f32
  float* ws  = (float*)d_ws;                // needs ~19.4 MB

  k_fact <<<1024, 256, 0, stream>>>(x, p, ws);
  k_solve<<<1024,  64, 0, stream>>>(x, ws);
  k_out  <<<dim3(8,64,4), 256, 0, stream>>>(x, ws, out);
}

// Round 2
// 645.694 us; speedup vs baseline: 1.1499x; 1.1499x over previous
//
#include <hip/hip_runtime.h>

#define IS2f 0.70710678118654752440f

// workspace offsets in floats
#define WS_Z   0ul          // 1024 * 2048
#define WS_G   2097152ul    // 1024 * 1024
#define WS_H   3145728ul    // 1024 * 1024
#define WS_SU  4194304ul    // 131072: [ci][b][j][c][l]
#define WS_VV  4325376ul    // 524288: [ci][b][j][l][n]
#define WS_B   4849664ul    // optional: 1024 * 8192 (32 MB)

// single-wave compiler memory barrier: LDS ops within one wave execute in
// issue order in HW; we only need to stop compiler reordering/caching.
#define WSYNC() asm volatile("" ::: "memory")

__device__ __forceinline__ void decode_pid(int pid, int& ci, int& b, int& l, int& L){
  if (pid < 512)      { ci = 0; b = pid >> 7; l = pid & 127; L = 128; }
  else if (pid < 768) { int q = pid - 512; ci = 1; b = q >> 6; l = q & 63; L = 64; }
  else                { int q = pid - 768; ci = 2; b = q >> 6; l = q & 63; L = 64; }
}
__device__ __forceinline__ int su_base(int ci){ return ci==0 ? 0 : (ci==1 ? 65536 : 98304); }
__device__ __forceinline__ int vv_base(int ci){ return ci==0 ? 0 : (ci==1 ? 262144 : 393216); }

// ---------------------------------------------------------------------------
// Kernel 1: per problem (ci,b,l): M (64x256) -> Z=M*p (64x32), G=Z^T Z,
// B=Z^T M (LDS; optionally stored), H=B B^T.  Store Z,G,H(,B) to ws.
// ---------------------------------------------------------------------------
__global__ __launch_bounds__(256) void k_fact(const float* __restrict__ x,
                                              const float* __restrict__ p,
                                              float* __restrict__ ws, int storeB){
  __shared__ __align__(16) float Ms[64*256];
  __shared__ __align__(16) float Zs[64*32];
  __shared__ float Bt[256*33];               // B transposed: Bt[n][k], pad 33
  __shared__ __align__(16) float Ps[256*32];

  int pid = blockIdx.x, tid = threadIdx.x;
  int ci,b,l,L; decode_pid(pid,ci,b,l,L);

  // stage p (256x32)
  {
    const float4* p4 = (const float4*)p;
    float4* Ps4 = (float4*)Ps;
    #pragma unroll
    for (int e=0;e<8;++e) Ps4[tid + 256*e] = p4[tid + 256*e];
  }
  // load M with on-the-fly Haar combine.  x f4 layout: ((b*256+t)*64+c)*64+g
  const float4* x4 = (const float4*)x;
  float4* Ms4 = (float4*)Ms;
  if (ci == 0){
    size_t base = ((size_t)(b*256 + 2*l) * 64) * 64;
    #pragma unroll
    for (int e=0;e<16;++e){
      int f = tid + 256*e;
      float4 A = x4[base + f];
      float4 Bv = x4[base + 4096 + f];
      float4 m;
      m.x=(A.x-Bv.x)*IS2f; m.y=(A.y-Bv.y)*IS2f; m.z=(A.z-Bv.z)*IS2f; m.w=(A.w-Bv.w)*IS2f;
      Ms4[f] = m;
    }
  } else {
    float sg = (ci==1) ? -0.5f : 0.5f;
    size_t base = ((size_t)(b*256 + 4*l) * 64) * 64;
    #pragma unroll
    for (int e=0;e<16;++e){
      int f = tid + 256*e;
      float4 A = x4[base + f];
      float4 B1 = x4[base + 4096 + f];
      float4 C1 = x4[base + 8192 + f];
      float4 D1 = x4[base + 12288 + f];
      float4 m;
      m.x=(A.x+B1.x)*0.5f + (C1.x+D1.x)*sg;
      m.y=(A.y+B1.y)*0.5f + (C1.y+D1.y)*sg;
      m.z=(A.z+B1.z)*0.5f + (C1.z+D1.z)*sg;
      m.w=(A.w+B1.w)*0.5f + (C1.w+D1.w)*sg;
      Ms4[f] = m;
    }
  }
  __syncthreads();

  // Z[c][k] = sum_n M[c][n] * p[n][k]
  {
    int k = tid & 31, c0 = tid >> 5;
    float acc[8] = {0,0,0,0,0,0,0,0};
    #pragma unroll 4
    for (int n4=0;n4<64;++n4){
      float p0 = Ps[(4*n4+0)*32 + k];
      float p1 = Ps[(4*n4+1)*32 + k];
      float p2 = Ps[(4*n4+2)*32 + k];
      float p3 = Ps[(4*n4+3)*32 + k];
      #pragma unroll
      for (int i=0;i<8;++i){
        float4 m = Ms4[(c0*8+i)*64 + n4];
        acc[i] += m.x*p0 + m.y*p1 + m.z*p2 + m.w*p3;
      }
    }
    #pragma unroll
    for (int i=0;i<8;++i){
      int c = c0*8 + i;
      Zs[c*32+k] = acc[i];
      ws[WS_Z + (size_t)pid*2048 + c*32 + k] = acc[i];
    }
  }
  __syncthreads();

  // G = Z^T Z (32x32)
  #pragma unroll
  for (int e=0;e<4;++e){
    int jk = tid + 256*e; int j = jk>>5, kk = jk&31;
    float a = 0.f;
    #pragma unroll 4
    for (int c=0;c<64;++c) a += Zs[c*32+j]*Zs[c*32+kk];
    ws[WS_G + (size_t)pid*1024 + jk] = a;
  }
  // B[k][n] = sum_c Z[c][k] M[c][n]  -> Bt[n][k]
  {
    int n4 = tid & 63, kg = tid >> 6;
    #pragma unroll
    for (int kq=0;kq<8;++kq){
      int kk = kg*8 + kq;
      float ax=0.f, ay=0.f, az=0.f, aw=0.f;
      #pragma unroll 4
      for (int c=0;c<64;++c){
        float zv = Zs[c*32+kk];
        float4 mv = Ms4[c*64 + n4];
        ax += zv*mv.x; ay += zv*mv.y; az += zv*mv.z; aw += zv*mv.w;
      }
      Bt[(n4*4+0)*33 + kk] = ax;
      Bt[(n4*4+1)*33 + kk] = ay;
      Bt[(n4*4+2)*33 + kk] = az;
      Bt[(n4*4+3)*33 + kk] = aw;
    }
  }
  __syncthreads();

  if (storeB){
    int n = tid;
    #pragma unroll 4
    for (int k=0;k<32;++k)
      ws[WS_B + (size_t)pid*8192 + k*256 + n] = Bt[n*33 + k];
  }

  // H = B B^T (32x32)
  #pragma unroll
  for (int e=0;e<4;++e){
    int jk = tid + 256*e; int j = jk>>5, kk = jk&31;
    float a = 0.f;
    #pragma unroll 4
    for (int n=0;n<256;++n) a += Bt[n*33+j]*Bt[n*33+kk];
    ws[WS_H + (size_t)pid*1024 + jk] = a;
  }
}

// ---------------------------------------------------------------------------
// Kernel 2: per problem, 1 wave, wave-synchronous (no s_barrier).
// Cholesky G=R^T R, W = R^-T H R^-1, parallel cyclic Jacobi, top-2;
// g=R^-1 w, u=Z g, vh = g^T B / s (or stream x).
// ---------------------------------------------------------------------------
#define NSWEEP 5

__global__ __launch_bounds__(64) void k_solve(const float* __restrict__ x,
                                              float* __restrict__ ws, int useB){
  __shared__ float Gs[32*33];
  __shared__ float Hs[32*33];
  __shared__ float Vsh[32*33];
  __shared__ float cA[16], sA[16];
  __shared__ int   pA[16], qA[16];
  __shared__ float rdg[32];
  __shared__ float sD;
  __shared__ float rr2[2][32], gg[2][32];
  __shared__ float us[2][64];
  __shared__ int   topi[2];
  __shared__ float topl[2];

  int pid = blockIdx.x, lane = threadIdx.x;
  int ci,b,l,L; decode_pid(pid,ci,b,l,L);
  int jlane = lane & 31, hlf = lane >> 5;

  #pragma unroll
  for (int e=0;e<16;++e){
    int idx = lane + 64*e; int i = idx>>5, j = idx&31;
    Gs[i*33+j]  = ws[WS_G + (size_t)pid*1024 + idx];
    Hs[i*33+j]  = ws[WS_H + (size_t)pid*1024 + idx];
    Vsh[i*33+j] = (i==j) ? 1.f : 0.f;
  }
  WSYNC();

  // Cholesky (upper), right-looking: G = R^T R
  for (int k=0;k<32;++k){
    if (lane == 0){ float d = sqrtf(Gs[k*33+k]); Gs[k*33+k] = d; sD = 1.f/d; }
    WSYNC();
    if (lane > k && lane < 32) Gs[k*33+lane] *= sD;
    WSYNC();
    for (int i=k+1+hlf; i<32; i+=2)
      if (jlane >= i) Gs[i*33+jlane] -= Gs[k*33+i]*Gs[k*33+jlane];
    WSYNC();
  }
  if (lane < 32) rdg[lane] = 1.f / Gs[lane*33+lane];
  WSYNC();

  // X = R^-T H  (solve R^T X = H, right-looking, in place)
  for (int i=0;i<32;++i){
    if (lane < 32) Hs[i*33+lane] *= rdg[i];
    WSYNC();
    for (int m=i+1+hlf; m<32; m+=2)
      Hs[m*33+jlane] -= Gs[i*33+m]*Hs[i*33+jlane];
    WSYNC();
  }
  // W = X R^-1  (solve W R = X, right-looking over columns, in place)
  for (int j=0;j<32;++j){
    if (lane < 32) Hs[lane*33+j] *= rdg[j];
    WSYNC();
    for (int m=j+1+hlf; m<32; m+=2)
      Hs[jlane*33+m] -= Gs[j*33+m]*Hs[jlane*33+j];
    WSYNC();
  }

  // parallel cyclic Jacobi: reads-then-writes per phase, wave-sync only
  for (int sw=0; sw<NSWEEP; ++sw){
    for (int r=0; r<31; ++r){
      if (lane < 16){
        int pp, qq;
        if (lane == 0){ pp = r; qq = 31; }
        else { pp = (r + lane) % 31; qq = (r + 31 - lane) % 31; }
        float app = Hs[pp*33+pp], aqq = Hs[qq*33+qq], apq = Hs[pp*33+qq];
        float cc = 1.f, ss = 0.f;
        if (fabsf(apq) > 1e-28f){
          float tau = (aqq - app) / (2.f*apq);
          float tt  = ((tau >= 0.f) ? 1.f : -1.f) / (fabsf(tau) + sqrtf(1.f + tau*tau));
          cc = 1.f / sqrtf(1.f + tt*tt);
          ss = tt * cc;
        }
        cA[lane]=cc; sA[lane]=ss; pA[lane]=pp; qA[lane]=qq;
      }
      WSYNC();
      // row phase: rows p,q mixed, all columns
      {
        float wp[8], wq[8], cs[8], sn[8]; int pi[8], qi[8];
        #pragma unroll
        for (int e=0;e<8;++e){
          int m = hlf + 2*e;
          pi[e]=pA[m]; qi[e]=qA[m]; cs[e]=cA[m]; sn[e]=sA[m];
          wp[e]=Hs[pi[e]*33+jlane]; wq[e]=Hs[qi[e]*33+jlane];
        }
        WSYNC();
        #pragma unroll
        for (int e=0;e<8;++e){
          Hs[pi[e]*33+jlane] = cs[e]*wp[e]-sn[e]*wq[e];
          Hs[qi[e]*33+jlane] = sn[e]*wp[e]+cs[e]*wq[e];
        }
      }
      WSYNC();
      // col phase: cols p,q mixed, all rows; V too
      {
        float hp[8], hq[8], vp[8], vq[8], cs[8], sn[8]; int pi[8], qi[8];
        #pragma unroll
        for (int e=0;e<8;++e){
          int m = hlf + 2*e;
          pi[e]=pA[m]; qi[e]=qA[m]; cs[e]=cA[m]; sn[e]=sA[m];
          hp[e]=Hs[jlane*33+pi[e]];  hq[e]=Hs[jlane*33+qi[e]];
          vp[e]=Vsh[jlane*33+pi[e]]; vq[e]=Vsh[jlane*33+qi[e]];
        }
        WSYNC();
        #pragma unroll
        for (int e=0;e<8;++e){
          Hs[jlane*33+pi[e]]  = cs[e]*hp[e]-sn[e]*hq[e];
          Hs[jlane*33+qi[e]]  = sn[e]*hp[e]+cs[e]*hq[e];
          Vsh[jlane*33+pi[e]] = cs[e]*vp[e]-sn[e]*vq[e];
          Vsh[jlane*33+qi[e]] = sn[e]*vp[e]+cs[e]*vq[e];
        }
      }
      WSYNC();
    }
  }

  // top-2 eigenvalues
  if (lane == 0){
    float b0 = -1e30f; int i0 = 0;
    for (int i=0;i<32;++i){ float d = Hs[i*33+i]; if (d > b0){ b0 = d; i0 = i; } }
    float b1 = -1e30f; int i1 = (i0==0) ? 1 : 0;
    for (int i=0;i<32;++i){ if (i==i0) continue; float d = Hs[i*33+i]; if (d > b1){ b1 = d; i1 = i; } }
    topi[0]=i0; topi[1]=i1; topl[0]=b0; topl[1]=b1;
  }
  WSYNC();

  // back-solve R g = w for both eigvecs (jj = lane>>5)
  {
    int jj = hlf, ii = jlane;
    rr2[jj][ii] = Vsh[ii*33 + topi[jj]];
    WSYNC();
    for (int i=31;i>=0;--i){
      if (ii == i) gg[jj][i] = rr2[jj][i] * rdg[i];
      WSYNC();
      if (ii < i) rr2[jj][ii] -= Gs[ii*33+i] * gg[jj][i];
      WSYNC();
    }
  }
  WSYNC();

  float s0 = sqrtf(fmaxf(topl[0], 0.f)); if (s0 < 1e-12f) s0 = 1e-12f;
  float s1 = sqrtf(fmaxf(topl[1], 0.f)); if (s1 < 1e-12f) s1 = 1e-12f;

  // u = Z g (lane = c)
  {
    const float4* Z4 = (const float4*)(ws + WS_Z + (size_t)pid*2048);
    float u0 = 0.f, u1 = 0.f;
    #pragma unroll
    for (int k4=0;k4<8;++k4){
      float4 z = Z4[lane*8 + k4];
      u0 += z.x*gg[0][k4*4+0] + z.y*gg[0][k4*4+1] + z.z*gg[0][k4*4+2] + z.w*gg[0][k4*4+3];
      u1 += z.x*gg[1][k4*4+0] + z.y*gg[1][k4*4+1] + z.z*gg[1][k4*4+2] + z.w*gg[1][k4*4+3];
    }
    us[0][lane] = u0; us[1][lane] = u1;
    ws[WS_SU + su_base(ci) + ((size_t)(b*2+0)*64 + lane)*L + l] = s0*u0;
    ws[WS_SU + su_base(ci) + ((size_t)(b*2+1)*64 + lane)*L + l] = s1*u1;
  }
  WSYNC();

  float i0 = 1.f/s0, i1 = 1.f/s1;
  size_t vb0 = WS_VV + vv_base(ci) + ((size_t)(b*2+0)*L + l)*256 + lane*4;
  size_t vb1 = WS_VV + vv_base(ci) + ((size_t)(b*2+1)*L + l)*256 + lane*4;

  if (useB){
    // vh_j = (g_j^T B) / s_j
    const float4* B4 = (const float4*)(ws + WS_B + (size_t)pid*8192);
    float a0x=0,a0y=0,a0z=0,a0w=0, a1x=0,a1y=0,a1z=0,a1w=0;
    #pragma unroll 8
    for (int k=0;k<32;++k){
      float4 bv = B4[(size_t)k*64 + lane];
      float g0 = gg[0][k], g1 = gg[1][k];
      a0x += g0*bv.x; a0y += g0*bv.y; a0z += g0*bv.z; a0w += g0*bv.w;
      a1x += g1*bv.x; a1y += g1*bv.y; a1z += g1*bv.z; a1w += g1*bv.w;
    }
    float4* w0 = (float4*)(ws + vb0);
    float4* w1 = (float4*)(ws + vb1);
    float4 r0; r0.x=a0x*i0; r0.y=a0y*i0; r0.z=a0z*i0; r0.w=a0w*i0;
    float4 r1; r1.x=a1x*i1; r1.y=a1y*i1; r1.z=a1z*i1; r1.w=a1w*i1;
    *w0 = r0; *w1 = r1;
  } else {
    // vh_j = u_j^T M / s_j, streaming x
    float a0x=0,a0y=0,a0z=0,a0w=0, a1x=0,a1y=0,a1z=0,a1w=0;
    const float4* x4 = (const float4*)x;
    if (ci == 0){
      size_t base = ((size_t)(b*256 + 2*l) * 64) * 64;
      #pragma unroll 2
      for (int c=0;c<64;++c){
        float4 A  = x4[base + c*64 + lane];
        float4 Bv = x4[base + 4096 + c*64 + lane];
        float mx=(A.x-Bv.x)*IS2f, my=(A.y-Bv.y)*IS2f, mz=(A.z-Bv.z)*IS2f, mw=(A.w-Bv.w)*IS2f;
        float uc0 = us[0][c], uc1 = us[1][c];
        a0x += uc0*mx; a0y += uc0*my; a0z += uc0*mz; a0w += uc0*mw;
        a1x += uc1*mx; a1y += uc1*my; a1z += uc1*mz; a1w += uc1*mw;
      }
    } else {
      float sg = (ci==1) ? -0.5f : 0.5f;
      size_t base = ((size_t)(b*256 + 4*l) * 64) * 64;
      #pragma unroll 2
      for (int c=0;c<64;++c){
        float4 A  = x4[base + c*64 + lane];
        float4 B1 = x4[base + 4096 + c*64 + lane];
        float4 C1 = x4[base + 8192 + c*64 + lane];
        float4 D1 = x4[base + 12288 + c*64 + lane];
        float mx=(A.x+B1.x)*0.5f + (C1.x+D1.x)*sg;
        float my=(A.y+B1.y)*0.5f + (C1.y+D1.y)*sg;
        float mz=(A.z+B1.z)*0.5f + (C1.z+D1.z)*sg;
        float mw=(A.w+B1.w)*0.5f + (C1.w+D1.w)*sg;
        float uc0 = us[0][c], uc1 = us[1][c];
        a0x += uc0*mx; a0y += uc0*my; a0z += uc0*mz; a0w += uc0*mw;
        a1x += uc1*mx; a1y += uc1*my; a1z += uc1*mz; a1w += uc1*mw;
      }
    }
    ws[vb0+0]=a0x*i0; ws[vb0+1]=a0y*i0; ws[vb0+2]=a0z*i0; ws[vb0+3]=a0w*i0;
    ws[vb1+0]=a1x*i1; ws[vb1+1]=a1y*i1; ws[vb1+2]=a1z*i1; ws[vb1+3]=a1w*i1;
  }
}

// ---------------------------------------------------------------------------
// Kernel 3: writer (unchanged).
// ---------------------------------------------------------------------------
__global__ __launch_bounds__(256) void k_out(const float* __restrict__ x,
                                             const float* __restrict__ ws,
                                             float* __restrict__ out){
  __shared__ float d1[128*33];
  __shared__ float d2[64*33];
  __shared__ float a2s[64*33];
  __shared__ float Vs[2*128*33];   // also aliased as a1 during Haar
  __shared__ float Us[512];

  int nt = blockIdx.x, c = blockIdx.y, b = blockIdx.z;
  int n0 = nt * 32, tid = threadIdx.x;
  float* a1 = Vs;

  const float4* x4 = (const float4*)x;
  #pragma unroll
  for (int e=0;e<4;++e){
    int f = tid + 256*e; int l1 = f>>3, d4 = f&7;
    size_t r = ((size_t)(b*256 + 2*l1)*64 + c)*64 + (n0>>2) + d4;
    float4 A = x4[r], Bv = x4[r + 4096];
    int o = l1*33 + 4*d4;
    d1[o+0]=(A.x-Bv.x)*IS2f; d1[o+1]=(A.y-Bv.y)*IS2f; d1[o+2]=(A.z-Bv.z)*IS2f; d1[o+3]=(A.w-Bv.w)*IS2f;
    a1[o+0]=(A.x+Bv.x)*IS2f; a1[o+1]=(A.y+Bv.y)*IS2f; a1[o+2]=(A.z+Bv.z)*IS2f; a1[o+3]=(A.w+Bv.w)*IS2f;
  }
  __syncthreads();
  #pragma unroll
  for (int e=0;e<2;++e){
    int f = tid + 256*e; int l2 = f>>3, d4 = f&7;
    #pragma unroll
    for (int j=0;j<4;++j){
      int dn = 4*d4 + j;
      float aa = a1[(2*l2)*33 + dn], bb = a1[(2*l2+1)*33 + dn];
      d2[l2*33+dn]  = (aa-bb)*IS2f;
      a2s[l2*33+dn] = (aa+bb)*IS2f;
    }
  }
  #pragma unroll
  for (int e=0;e<2;++e){
    int idx = tid + 256*e;
    int j, l, L, so;
    if (idx < 256)      { j=idx>>7;        l=idx&127; L=128; so=0; }
    else if (idx < 384) { j=(idx-256)>>6;  l=idx&63;  L=64;  so=65536; }
    else                { j=(idx-384)>>6;  l=idx&63;  L=64;  so=98304; }
    Us[idx] = ws[WS_SU + so + ((size_t)(b*2+j)*64 + c)*L + l];
  }
  __syncthreads();

  for (int cc=0; cc<3; ++cc){
    int L   = (cc==0) ? 128 : 64;
    int pad = 256 - L;
    int sb  = cc*3;
    int uo  = (cc==0) ? 0 : (cc==1) ? 256 : 384;
    const float* cf = (cc==0) ? d1 : (cc==1) ? d2 : a2s;

    int iters = (2*L*32) >> 8;
    for (int e=0;e<iters;++e){
      int idx = tid + 256*e;
      int j = (idx >= L*32) ? 1 : 0;
      int rem = idx - j*L*32;
      int ll = rem >> 5, dn = rem & 31;
      Vs[j*4224 + ll*33 + dn] =
        ws[WS_VV + vv_base(cc) + ((size_t)(b*2+j)*L + ll)*256 + n0 + dn];
    }
    __syncthreads();

    int l = tid - pad;
    bool inr = (l >= 0);
    size_t obase = (size_t)sb*16777216 + (size_t)b*4194304 + (size_t)c*65536
                 + (size_t)n0*256 + tid;
    #pragma unroll 4
    for (int dn=0; dn<32; ++dn){
      float v0 = 0.f, v1 = 0.f, rv = 0.f;
      if (inr){
        float q0 = Us[uo + l]     * Vs[l*33 + dn];
        float q1 = Us[uo + L + l] * Vs[4224 + l*33 + dn];
        v0 = q0; v1 = q1;
        rv = cf[l*33 + dn] - q0 - q1;
      }
      out[obase + dn*256]            = v0;
      out[obase + dn*256 + 16777216] = v1;
      out[obase + dn*256 + 33554432] = rv;
    }
    __syncthreads();
  }
}

// ---------------------------------------------------------------------------
extern "C" void kernel_launch(void* const* d_in, const int* in_sizes, int n_in,
                              void* d_out, int out_size, void* d_ws, size_t ws_size,
                              hipStream_t stream) {
  const float* x = (const float*)d_in[0];   // (4,256,64,256) f32
  const float* p = (const float*)d_in[1];   // (256,32) f32
  float* out = (float*)d_out;               // (9,4,64,256,256) f32
  float* ws  = (float*)d_ws;

  int useB = (ws_size >= (size_t)(WS_B + 1024ull*8192ull) * 4ull) ? 1 : 0;

  k_fact <<<1024, 256, 0, stream>>>(x, p, ws, useB);
  k_solve<<<1024,  64, 0, stream>>>(x, ws, useB);
  k_out  <<<dim3(8,64,4), 256, 0, stream>>>(x, ws, out);
}